// Round 6
// baseline (347.910 us; speedup 1.0000x reference)
//
#include <hip/hip_runtime.h>
#include <math.h>

// Problem constants (B=2, S=2048 -> N=4096 tokens)
#define NTOK 4096
#define DDIM 512
#define HDIM 2048
#define NEXP 16

// Fragment-tiled layouts: elem(e_or_t, row, k) =
//   ((tile16 * CK + (k>>3)) * 128) + (row&15)*8 + (k&7)
// so a 64-lane b128 load (lane*16B) fetches rows r0..r0+15 x k-chunk32 — one
// MFMA fragment set, fully coalesced. No LDS needed in the GEMM K-loop.

// Workspace layout (bytes). Total ~115 MB (<= known-good 125.8 MB).
#define WS_COUNTS    0u
#define WS_OFFSETS   256u
#define WS_NTILES    512u
#define WS_TM        768u          // <=80 ints
#define WS_EPOS      4096u         // NTOK*2 ints (32 KB)
#define WS_TOK       36864u        // NEXP*NTOK ints (256 KB)
#define WS_WL        299008u       // NEXP*NTOK floats (256 KB)
#define WS_XA        1048576u      // tiled A for gemm1: 80*128*512 bf16 = 10.5 MB
#define WS_W1T       11534336u     // tiled [e][nt128][c64][16][8] bf16 = 33.5 MB
#define WS_W2T       45088768u     // tiled [e][nt32][c256][16][8] bf16 = 33.5 MB
#define WS_HB        78643200u     // tiled [t80][sub8][c256][16][8] bf16 = 41.9 MB
#define WS_YB        WS_W1T        // ybuf [2][8192][512] bf16 = 16.8 MB, aliases W1T
                                   // (W1T dead after gemm1; stream is serial)

typedef __attribute__((ext_vector_type(8))) short short8;
typedef __attribute__((ext_vector_type(4))) float floatx4;
typedef unsigned short ushort_t;

__device__ __forceinline__ ushort_t f2bf(float f) {
    unsigned u = __float_as_uint(f);
    u += 0x7fffu + ((u >> 16) & 1u);   // round-to-nearest-even
    return (ushort_t)(u >> 16);
}
__device__ __forceinline__ float bf2f(ushort_t u) {
    return __uint_as_float((unsigned)u << 16);
}

// Raw barrier: drain LDS only, leave register global-loads in flight
// (m139-verified idiom; __syncthreads would conservatively drain vmcnt).
#define BAR_LGKM() asm volatile("s_waitcnt lgkmcnt(0)\n\ts_barrier" ::: "memory")

// ---------------- gating: 8 tokens/block (fp32 logits match reference) -----
__global__ __launch_bounds__(256) void gating_kernel(
    const float* __restrict__ x, const float* __restrict__ Wg,
    const float* __restrict__ bg, int* __restrict__ counts,
    int* __restrict__ tok_list, float* __restrict__ w_list,
    int* __restrict__ epos)
{
    __shared__ float xs[8][520];
    __shared__ float lsm[8][16][2];
    const int tid = threadIdx.x;
    const int t0 = blockIdx.x * 8;
    const float* xg = x + (size_t)t0 * DDIM;
    #pragma unroll
    for (int p = 0; p < 4; ++p) {
        const int idx = p * 1024 + tid * 4;
        *(float4*)&xs[idx >> 9][idx & 511] = *(const float4*)(xg + idx);
    }
    __syncthreads();
    const int tl = tid >> 5, e = (tid >> 1) & 15, h = tid & 1;
    float a0 = 0.f, a1 = 0.f, a2 = 0.f, a3 = 0.f;
    #pragma unroll 8
    for (int it = 0; it < 64; ++it) {
        const int d = h * 256 + it * 4;
        const float4 xv = *(const float4*)&xs[tl][d];
        a0 = fmaf(xv.x, Wg[(d + 0) * 16 + e], a0);
        a1 = fmaf(xv.y, Wg[(d + 1) * 16 + e], a1);
        a2 = fmaf(xv.z, Wg[(d + 2) * 16 + e], a2);
        a3 = fmaf(xv.w, Wg[(d + 3) * 16 + e], a3);
    }
    lsm[tl][e][h] = (a0 + a1) + (a2 + a3);
    __syncthreads();
    if ((tid & 31) == 0) {
        float l[16];
        #pragma unroll
        for (int j = 0; j < NEXP; ++j) l[j] = lsm[tl][j][0] + lsm[tl][j][1] + bg[j];
        float m = -1e30f;
        #pragma unroll
        for (int j = 0; j < NEXP; ++j) m = fmaxf(m, l[j]);
        float s = 0.f;
        #pragma unroll
        for (int j = 0; j < NEXP; ++j) s += __expf(l[j] - m);
        int i0 = 0; float v0 = -1e30f;
        #pragma unroll
        for (int j = 0; j < NEXP; ++j)
            if (l[j] > v0) { v0 = l[j]; i0 = j; }
        int i1 = -1; float v1 = -1e30f;
        #pragma unroll
        for (int j = 0; j < NEXP; ++j)
            if (j != i0 && l[j] > v1) { v1 = l[j]; i1 = j; }
        const float w0 = __expf(v0 - m) / s;
        const float w1 = __expf(v1 - m) / s;
        const int t = t0 + tl;
        int p0 = atomicAdd(&counts[i0], 1);
        tok_list[i0 * NTOK + p0] = t;
        w_list[i0 * NTOK + p0] = w0;
        epos[t * 2 + 0] = (i0 << 16) | p0;
        int p1 = atomicAdd(&counts[i1], 1);
        tok_list[i1 * NTOK + p1] = t;
        w_list[i1 * NTOK + p1] = w1;
        epos[t * 2 + 1] = (i1 << 16) | p1;
    }
}

// ---- weight transpose+convert, pipelined: 8 tiles/block, dbuf LDS, reg
// prefetch across raw barrier. 1024 blocks (512 W1 + 512 W2 slabs). ----------
__global__ __launch_bounds__(256) void wtrans_kernel(
    const float* __restrict__ W1, const float* __restrict__ W2,
    ushort_t* __restrict__ W1t, ushort_t* __restrict__ W2t)
{
    __shared__ ushort_t lds[2][64 * 68];
    const int tid = threadIdx.x;
    int b = blockIdx.x;
    const float* src; ushort_t* dst; int C, NT, CK, e, n0, kt0;
    if (b < 512) {                 // W1: [512 k][2048 n]; block = 64n x all-k
        e = b >> 5; const int ct = b & 31;
        src = W1; dst = W1t; C = HDIM; NT = 128; CK = 64;
        n0 = ct << 6; kt0 = 0;
    } else {                       // W2: [2048 k][512 n]; block = 64n x 512k slab
        b -= 512;
        e = b >> 5; const int u = b & 31;
        src = W2; dst = W2t; C = DDIM; NT = 32; CK = 256;
        n0 = (u & 7) << 6; kt0 = (u >> 3) << 3;
    }
    const float* sp = src + (size_t)e * (DDIM * HDIM) + n0;
    const int qq = tid >> 4, cc4 = (tid & 15) << 2;
    const int w = tid >> 6, l = tid & 63;

    float4 v[2][4];
    #pragma unroll
    for (int p = 0; p < 4; ++p)
        v[0][p] = *(const float4*)(sp + (size_t)((kt0 << 6) + qq + (p << 4)) * C + cc4);

    #pragma unroll
    for (int i = 0; i < 8; ++i) {
        ushort_t* lb = lds[i & 1];
        const float4* vv = v[i & 1];
        #pragma unroll
        for (int p = 0; p < 4; ++p) {
            const int r = qq + (p << 4);
            *(ushort4*)(lb + r * 68 + cc4) = make_ushort4(
                f2bf(vv[p].x), f2bf(vv[p].y), f2bf(vv[p].z), f2bf(vv[p].w));
        }
        if (i < 7) {               // prefetch tile i+1 into the other reg set
            const int k0n = (kt0 + i + 1) << 6;
            #pragma unroll
            for (int p = 0; p < 4; ++p)
                v[(i + 1) & 1][p] =
                    *(const float4*)(sp + (size_t)(k0n + qq + (p << 4)) * C + cc4);
        }
        BAR_LGKM();                // loads stay in flight across this
        const int kc16 = (kt0 + i) << 3;
        ushort_t* run = dst + (((size_t)e * NT + (n0 >> 4) + w) * CK + kc16) * 128;
        #pragma unroll
        for (int p = 0; p < 2; ++p) {
            const int lidx = l + (p << 6);
            const int kc = lidx >> 4, nl = lidx & 15;
            const int col = (w << 4) + nl;
            short8 o;
            #pragma unroll
            for (int j = 0; j < 8; ++j)
                o[j] = (short)lb[((kc << 3) + j) * 68 + col];
            *(short8*)(run + (size_t)lidx * 8) = o;
        }
        // buffer b reused 2 iters (2 barriers) later -> safe; no 2nd barrier.
    }
}

// offsets prefix-scan + 128-row tile list, wave-parallel
__global__ void scan_kernel(const int* __restrict__ counts, int* __restrict__ offsets,
                            int* __restrict__ tm, int* __restrict__ ntiles)
{
    const int lane = threadIdx.x;
    int c = (lane < NEXP) ? counts[lane] : 0;
    int t = (c + 127) >> 7;
    int ic = c, it = t;
    #pragma unroll
    for (int off = 1; off < 16; off <<= 1) {
        const int pc = __shfl_up(ic, off, 64);
        const int pt = __shfl_up(it, off, 64);
        if (lane >= off) { ic += pc; it += pt; }
    }
    if (lane < NEXP) {
        offsets[lane] = ic - c;
        if (lane == NEXP - 1) { offsets[NEXP] = ic; ntiles[0] = it; }
        const int tb = it - t;
        for (int i = 0; i < t; ++i) tm[tb + i] = (lane << 16) | i;
    }
}

// gather x rows (fp32) into fragment-tiled bf16 A, slot order per 128-tile.
__global__ __launch_bounds__(256) void gather_xa(
    const float* __restrict__ x, const int* __restrict__ tok_list,
    const int* __restrict__ counts, const int* __restrict__ tm,
    const int* __restrict__ ntiles, ushort_t* __restrict__ xa)
{
    const int b = blockIdx.x;
    if (b >= ntiles[0]) return;
    const int info = tm[b];
    const int e = info >> 16, m0 = (info & 0xffff) << 7;
    const int Me = counts[e];
    const int row = threadIdx.x >> 1;
    const int half = threadIdx.x & 1;
    const int kbase = blockIdx.y * 128 + half * 64;
    const int tok = tok_list[e * NTOK + min(m0 + row, Me - 1)];
    const float* src = x + (size_t)tok * DDIM + kbase;
    ushort_t* dstb = xa + (size_t)b * 65536 + (size_t)(row >> 4) * 8192 + (row & 15) * 8;
    #pragma unroll
    for (int q = 0; q < 16; ++q) {
        const int k = kbase + q * 4;
        const float4 v = *(const float4*)(src + q * 4);
        ushort4 o = make_ushort4(f2bf(v.x), f2bf(v.y), f2bf(v.z), f2bf(v.w));
        *(ushort4*)(dstb + (size_t)(k >> 3) * 128 + (k & 7)) = o;
    }
}

// ---- GEMM1: barrier-free K-loop, frags direct from global (tiled layouts) --
__global__ __launch_bounds__(256) void gemm1_mfma(
    const ushort_t* __restrict__ xa, const ushort_t* __restrict__ W1t,
    const float* __restrict__ b1, const int* __restrict__ tm,
    const int* __restrict__ ntiles, ushort_t* __restrict__ hb)
{
    const int t = blockIdx.y;
    if (t >= ntiles[0]) return;
    const int e = tm[t] >> 16;
    const int n0 = blockIdx.x << 7;
    const int tid = threadIdx.x, lane = tid & 63, w = tid >> 6;
    const int fm = lane & 15, fq = lane >> 4;
    const int wr = (w >> 1) << 6, wc = (w & 1) << 6;

    const ushort_t* baseA = xa + (size_t)t * 65536
                          + (size_t)((w >> 1) * 4) * 8192 + lane * 8;
    const ushort_t* baseB = W1t + ((size_t)e * 128 + (n0 >> 4) + (w & 1) * 4) * 8192
                          + lane * 8;

    floatx4 acc[4][4] = {};
    #pragma unroll 4
    for (int kc = 0; kc < 16; ++kc) {
        short8 af[4], bf[4];
        #pragma unroll
        for (int i = 0; i < 4; ++i)
            af[i] = *(const short8*)(baseA + i * 8192 + kc * 512);
        #pragma unroll
        for (int j = 0; j < 4; ++j)
            bf[j] = *(const short8*)(baseB + j * 8192 + kc * 512);
        #pragma unroll
        for (int i = 0; i < 4; ++i)
            #pragma unroll
            for (int j = 0; j < 4; ++j)
                acc[i][j] = __builtin_amdgcn_mfma_f32_16x16x32_bf16(
                    af[i], bf[j], acc[i][j], 0, 0, 0);
    }

    __shared__ ushort_t ls[128 * 128];
    #pragma unroll
    for (int j = 0; j < 4; ++j) {
        const float bias = b1[(size_t)e * HDIM + n0 + wc + j * 16 + fm];
        #pragma unroll
        for (int i = 0; i < 4; ++i)
            #pragma unroll
            for (int r = 0; r < 4; ++r) {
                const int row = wr + i * 16 + fq * 4 + r;
                ls[row * 128 + wc + j * 16 + fm] =
                    f2bf(fmaxf(acc[i][j][r] + bias, 0.f));
            }
    }
    __syncthreads();
    ushort_t* hbase = hb + (size_t)t * 262144 + (size_t)(n0 >> 3) * 128;
    #pragma unroll
    for (int p = 0; p < 8; ++p) {
        const int unit = tid + p * 256;
        const int row = unit >> 4, c16 = unit & 15;
        *(short8*)(hbase + (size_t)(row >> 4) * 32768 + (size_t)c16 * 128
                   + (row & 15) * 8) = *(const short8*)&ls[row * 128 + c16 * 8];
    }
}

// ---- GEMM2: same structure, K=2048 split-K=2, bf16 partials to ybuf -------
__global__ __launch_bounds__(256) void gemm2_mfma(
    const ushort_t* __restrict__ hb, const ushort_t* __restrict__ W2t,
    const float* __restrict__ b2, const float* __restrict__ w_list,
    const int* __restrict__ counts, const int* __restrict__ offsets,
    const int* __restrict__ tm, const int* __restrict__ ntiles,
    ushort_t* __restrict__ yb)
{
    const int t = blockIdx.y;
    if (t >= ntiles[0]) return;
    const int info = tm[t];
    const int e = info >> 16, m0 = (info & 0xffff) << 7;
    const int Me = counts[e], aoff = offsets[e];
    const int n0 = blockIdx.x << 7;
    const int kz = blockIdx.z;
    const int tid = threadIdx.x, lane = tid & 63, w = tid >> 6;
    const int fm = lane & 15, fq = lane >> 4;
    const int wr = (w >> 1) << 6, wc = (w & 1) << 6;

    const ushort_t* baseA = hb + (size_t)t * 262144
                          + (size_t)((w >> 1) * 4) * 32768 + kz * 16384 + lane * 8;
    const ushort_t* baseB = W2t + ((size_t)e * 32 + (n0 >> 4) + (w & 1) * 4) * 32768
                          + kz * 16384 + lane * 8;

    floatx4 acc[4][4] = {};
    #pragma unroll 4
    for (int kc = 0; kc < 32; ++kc) {
        short8 af[4], bf[4];
        #pragma unroll
        for (int i = 0; i < 4; ++i)
            af[i] = *(const short8*)(baseA + i * 32768 + kc * 512);
        #pragma unroll
        for (int j = 0; j < 4; ++j)
            bf[j] = *(const short8*)(baseB + j * 32768 + kc * 512);
        #pragma unroll
        for (int i = 0; i < 4; ++i)
            #pragma unroll
            for (int j = 0; j < 4; ++j)
                acc[i][j] = __builtin_amdgcn_mfma_f32_16x16x32_bf16(
                    af[i], bf[j], acc[i][j], 0, 0, 0);
    }

    __shared__ ushort_t ls[128 * 128];
    #pragma unroll
    for (int j = 0; j < 4; ++j) {
        const float bias = (kz == 0) ? b2[(size_t)e * DDIM + n0 + wc + j * 16 + fm] : 0.f;
        #pragma unroll
        for (int i = 0; i < 4; ++i)
            #pragma unroll
            for (int r = 0; r < 4; ++r) {
                const int row = wr + i * 16 + fq * 4 + r;
                const float gw = w_list[e * NTOK + min(m0 + row, Me - 1)];
                ls[row * 128 + wc + j * 16 + fm] = f2bf(gw * (acc[i][j][r] + bias));
            }
    }
    __syncthreads();
    ushort_t* ybase = yb + (size_t)kz * (8192 * 512) + n0;
    #pragma unroll
    for (int p = 0; p < 8; ++p) {
        const int unit = tid + p * 256;
        const int row = unit >> 4, c16 = unit & 15;
        if (m0 + row < Me)
            *(short8*)(ybase + (size_t)(aoff + m0 + row) * 512 + c16 * 8)
                = *(const short8*)&ls[row * 128 + c16 * 8];
    }
}

// out = LayerNorm(x + y[0][r0] + y[1][r0] + y[0][r1] + y[1][r1]) * gamma + beta
__global__ __launch_bounds__(256) void ln_kernel(
    const float* __restrict__ x, const ushort_t* __restrict__ yb,
    const int* __restrict__ epos, const int* __restrict__ offsets,
    const float* __restrict__ gamma, const float* __restrict__ beta,
    float* __restrict__ out)
{
    const int t = blockIdx.x * 4 + (threadIdx.x >> 6);
    const int lane = threadIdx.x & 63;
    const int d0 = lane * 8;

    const int p0 = epos[2 * t + 0];
    const int p1 = epos[2 * t + 1];
    const size_t r0 = (size_t)(offsets[p0 >> 16] + (p0 & 0xFFFF));
    const size_t r1 = (size_t)(offsets[p1 >> 16] + (p1 & 0xFFFF));

    const short8 y0 = *(const short8*)(yb + r0 * 512 + d0);
    const short8 y1 = *(const short8*)(yb + (size_t)8192 * 512 + r0 * 512 + d0);
    const short8 y2 = *(const short8*)(yb + r1 * 512 + d0);
    const short8 y3 = *(const short8*)(yb + (size_t)8192 * 512 + r1 * 512 + d0);
    float xv[8];
    *(float4*)&xv[0] = *(const float4*)(x + (size_t)t * DDIM + d0);
    *(float4*)&xv[4] = *(const float4*)(x + (size_t)t * DDIM + d0 + 4);

    float v[8];
    float s = 0.f;
    #pragma unroll
    for (int i = 0; i < 8; ++i) {
        v[i] = xv[i] + bf2f((ushort_t)y0[i]) + bf2f((ushort_t)y1[i])
                     + bf2f((ushort_t)y2[i]) + bf2f((ushort_t)y3[i]);
        s += v[i];
    }
    #pragma unroll
    for (int o = 32; o > 0; o >>= 1) s += __shfl_xor(s, o, 64);
    const float mu = s * (1.f / DDIM);
    float q = 0.f;
    #pragma unroll
    for (int i = 0; i < 8; ++i) { const float d_ = v[i] - mu; q = fmaf(d_, d_, q); }
    #pragma unroll
    for (int o = 32; o > 0; o >>= 1) q += __shfl_xor(q, o, 64);
    const float rstd = rsqrtf(q * (1.f / DDIM) + 1e-5f);

    float g[8], bt[8], o8[8];
    *(float4*)&g[0] = *(const float4*)(gamma + d0);
    *(float4*)&g[4] = *(const float4*)(gamma + d0 + 4);
    *(float4*)&bt[0] = *(const float4*)(beta + d0);
    *(float4*)&bt[4] = *(const float4*)(beta + d0 + 4);
    #pragma unroll
    for (int i = 0; i < 8; ++i) o8[i] = (v[i] - mu) * rstd * g[i] + bt[i];
    *(float4*)(out + (size_t)t * DDIM + d0) = *(float4*)&o8[0];
    *(float4*)(out + (size_t)t * DDIM + d0 + 4) = *(float4*)&o8[4];
}

extern "C" void kernel_launch(void* const* d_in, const int* in_sizes, int n_in,
                              void* d_out, int out_size, void* d_ws, size_t ws_size,
                              hipStream_t stream) {
    const float* x     = (const float*)d_in[0];
    const float* Wg    = (const float*)d_in[1];
    const float* bg    = (const float*)d_in[2];
    const float* W1    = (const float*)d_in[3];
    const float* b1    = (const float*)d_in[4];
    const float* W2    = (const float*)d_in[5];
    const float* b2    = (const float*)d_in[6];
    const float* gamma = (const float*)d_in[7];
    const float* beta  = (const float*)d_in[8];
    float* out = (float*)d_out;

    char* ws = (char*)d_ws;
    int*      counts   = (int*)(ws + WS_COUNTS);
    int*      offsets  = (int*)(ws + WS_OFFSETS);
    int*      ntiles   = (int*)(ws + WS_NTILES);
    int*      tm       = (int*)(ws + WS_TM);
    int*      epos     = (int*)(ws + WS_EPOS);
    int*      tok_list = (int*)(ws + WS_TOK);
    float*    w_list   = (float*)(ws + WS_WL);
    ushort_t* xa       = (ushort_t*)(ws + WS_XA);
    ushort_t* W1t      = (ushort_t*)(ws + WS_W1T);
    ushort_t* W2t      = (ushort_t*)(ws + WS_W2T);
    ushort_t* hb       = (ushort_t*)(ws + WS_HB);
    ushort_t* yb       = (ushort_t*)(ws + WS_YB);   // aliases W1t (dead by then)

    hipMemsetAsync(counts, 0, 64, stream);
    gating_kernel<<<512, 256, 0, stream>>>(x, Wg, bg, counts, tok_list, w_list, epos);
    wtrans_kernel<<<1024, 256, 0, stream>>>(W1, W2, W1t, W2t);
    scan_kernel<<<1, 64, 0, stream>>>(counts, offsets, tm, ntiles);
    gather_xa<<<dim3(80, 4), 256, 0, stream>>>(x, tok_list, counts, tm, ntiles, xa);
    gemm1_mfma<<<dim3(HDIM / 128, 80), 256, 0, stream>>>(
        xa, W1t, b1, tm, ntiles, hb);
    gemm2_mfma<<<dim3(DDIM / 128, 80, 2), 256, 0, stream>>>(
        hb, W2t, b2, w_list, counts, offsets, tm, ntiles, yb);
    ln_kernel<<<NTOK / 4, 256, 0, stream>>>(x, yb, epos, offsets, gamma, beta, out);
}

// Round 7
// 294.521 us; speedup vs baseline: 1.1813x; 1.1813x over previous
//
#include <hip/hip_runtime.h>
#include <math.h>

// Problem constants (B=2, S=2048 -> N=4096 tokens)
#define NTOK 4096
#define DDIM 512
#define HDIM 2048
#define NEXP 16

// Fragment-tiled layouts: elem(e_or_t, row, k) =
//   ((tile16 * CK + (k>>3)) * 128) + (row&15)*8 + (k&7)
// so a 64-lane b128 load (lane*16B) fetches rows r0..r0+15 x k-chunk32 — one
// MFMA fragment set, fully coalesced. No LDS needed in the GEMM K-loop.

// Workspace layout (bytes). counts padded: one counter per 64 B line.
#define WS_COUNTS    0u            // 16 lines x 64 B = 1 KB
#define WS_OFFSETS   1024u
#define WS_NTILES    1280u
#define WS_TM        1536u         // <=80 ints
#define WS_EPOS      4096u         // NTOK*2 ints (32 KB)
#define WS_TOK       36864u        // NEXP*NTOK ints (256 KB)
#define WS_WL        299008u       // NEXP*NTOK floats (256 KB)
#define WS_XA        1048576u      // tiled A for gemm1: 80*128*512 bf16 = 10.5 MB
#define WS_W1T       11534336u     // tiled [e][nt128][c64][16][8] bf16 = 33.5 MB
#define WS_W2T       45088768u     // tiled [e][nt32][c256][16][8] bf16 = 33.5 MB
#define WS_HB        78643200u     // tiled [t80][sub8][c256][16][8] bf16 = 41.9 MB
#define WS_YB        WS_W1T        // ybuf [2][8192][512] bf16, aliases W1T (dead)

typedef __attribute__((ext_vector_type(8))) short short8;
typedef __attribute__((ext_vector_type(4))) float floatx4;
typedef unsigned short ushort_t;

__device__ __forceinline__ ushort_t f2bf(float f) {
    unsigned u = __float_as_uint(f);
    u += 0x7fffu + ((u >> 16) & 1u);   // round-to-nearest-even
    return (ushort_t)(u >> 16);
}
__device__ __forceinline__ float bf2f(ushort_t u) {
    return __uint_as_float((unsigned)u << 16);
}

// Raw barrier: drain LDS only, leave register global-loads in flight.
#define BAR_LGKM() asm volatile("s_waitcnt lgkmcnt(0)\n\ts_barrier" ::: "memory")

// ---- fused prep: blocks 0..511 gating (8 tok), 512..1535 wtrans ------------
// Gating atomics: LDS histogram -> <=16 global atomicAdds per block, each to
// its own 64 B line (counts[e*16]). [R6 post-mortem: 8192 same-line atomics
// serialized on one L2 slice ~= the whole 66 us.]
__global__ __launch_bounds__(256) void prep_kernel(
    const float* __restrict__ x, const float* __restrict__ Wg,
    const float* __restrict__ bg, const float* __restrict__ W1,
    const float* __restrict__ W2, int* __restrict__ counts,
    int* __restrict__ tok_list, float* __restrict__ w_list,
    int* __restrict__ epos, ushort_t* __restrict__ W1t,
    ushort_t* __restrict__ W2t)
{
    __shared__ __align__(16) float smem[4416];   // 17.7 KB, both paths
    __shared__ int lcnt[16], lbase[16];
    const int tid = threadIdx.x;
    int bid = blockIdx.x;

    if (bid < 512) {
        // ---------------- gating ----------------
        float (*xs)[520] = (float(*)[520])smem;
        float (*lsm)[16][2] = (float(*)[16][2])(smem + 4160);
        const int t0 = bid * 8;
        const float* xg = x + (size_t)t0 * DDIM;
        #pragma unroll
        for (int p = 0; p < 4; ++p) {
            const int idx = p * 1024 + tid * 4;
            *(float4*)&xs[idx >> 9][idx & 511] = *(const float4*)(xg + idx);
        }
        if (tid < 16) lcnt[tid] = 0;
        __syncthreads();
        const int tl = tid >> 5, e = (tid >> 1) & 15, h = tid & 1;
        float a0 = 0.f, a1 = 0.f, a2 = 0.f, a3 = 0.f;
        #pragma unroll 8
        for (int it = 0; it < 64; ++it) {
            const int d = h * 256 + it * 4;
            const float4 xv = *(const float4*)&xs[tl][d];
            a0 = fmaf(xv.x, Wg[(d + 0) * 16 + e], a0);
            a1 = fmaf(xv.y, Wg[(d + 1) * 16 + e], a1);
            a2 = fmaf(xv.z, Wg[(d + 2) * 16 + e], a2);
            a3 = fmaf(xv.w, Wg[(d + 3) * 16 + e], a3);
        }
        lsm[tl][e][h] = (a0 + a1) + (a2 + a3);
        __syncthreads();

        int i0 = 0, i1 = -1, r0 = 0, r1 = 0;
        float w0 = 0.f, w1 = 0.f;
        const bool tokth = ((tid & 31) == 0);
        if (tokth) {
            float l[16];
            #pragma unroll
            for (int j = 0; j < NEXP; ++j) l[j] = lsm[tl][j][0] + lsm[tl][j][1] + bg[j];
            float m = -1e30f;
            #pragma unroll
            for (int j = 0; j < NEXP; ++j) m = fmaxf(m, l[j]);
            float s = 0.f;
            #pragma unroll
            for (int j = 0; j < NEXP; ++j) s += __expf(l[j] - m);
            float v0 = -1e30f;
            #pragma unroll
            for (int j = 0; j < NEXP; ++j)
                if (l[j] > v0) { v0 = l[j]; i0 = j; }
            float v1 = -1e30f;
            #pragma unroll
            for (int j = 0; j < NEXP; ++j)
                if (j != i0 && l[j] > v1) { v1 = l[j]; i1 = j; }
            w0 = __expf(v0 - m) / s;
            w1 = __expf(v1 - m) / s;
            r0 = atomicAdd(&lcnt[i0], 1);      // LDS atomics: local rank
            r1 = atomicAdd(&lcnt[i1], 1);
        }
        __syncthreads();
        if (tid < 16 && lcnt[tid] > 0)
            lbase[tid] = atomicAdd(&counts[tid * 16], lcnt[tid]);
        __syncthreads();
        if (tokth) {
            const int t = t0 + tl;
            const int p0 = lbase[i0] + r0;
            tok_list[i0 * NTOK + p0] = t;
            w_list[i0 * NTOK + p0] = w0;
            epos[t * 2 + 0] = (i0 << 16) | p0;
            const int p1 = lbase[i1] + r1;
            tok_list[i1 * NTOK + p1] = t;
            w_list[i1 * NTOK + p1] = w1;
            epos[t * 2 + 1] = (i1 << 16) | p1;
        }
        return;
    }

    // ---- weight transpose+convert, pipelined: 8 tiles/block, dbuf LDS ----
    bid -= 512;
    ushort_t (*lds)[64 * 68] = (ushort_t(*)[64 * 68])smem;
    const float* src; ushort_t* dst; int C, NT, CK, e, n0, kt0;
    if (bid < 512) {               // W1: [512 k][2048 n]; block = 64n x all-k
        e = bid >> 5; const int ct = bid & 31;
        src = W1; dst = W1t; C = HDIM; NT = 128; CK = 64;
        n0 = ct << 6; kt0 = 0;
    } else {                       // W2: [2048 k][512 n]; block = 64n x 512k slab
        bid -= 512;
        e = bid >> 5; const int u = bid & 31;
        src = W2; dst = W2t; C = DDIM; NT = 32; CK = 256;
        n0 = (u & 7) << 6; kt0 = (u >> 3) << 3;
    }
    const float* sp = src + (size_t)e * (DDIM * HDIM) + n0;
    const int qq = tid >> 4, cc4 = (tid & 15) << 2;
    const int w = tid >> 6, l = tid & 63;

    float4 v[2][4];
    #pragma unroll
    for (int p = 0; p < 4; ++p)
        v[0][p] = *(const float4*)(sp + (size_t)((kt0 << 6) + qq + (p << 4)) * C + cc4);

    #pragma unroll
    for (int i = 0; i < 8; ++i) {
        ushort_t* lb = lds[i & 1];
        const float4* vv = v[i & 1];
        #pragma unroll
        for (int p = 0; p < 4; ++p) {
            const int r = qq + (p << 4);
            *(ushort4*)(lb + r * 68 + cc4) = make_ushort4(
                f2bf(vv[p].x), f2bf(vv[p].y), f2bf(vv[p].z), f2bf(vv[p].w));
        }
        if (i < 7) {               // prefetch tile i+1 into the other reg set
            const int k0n = (kt0 + i + 1) << 6;
            #pragma unroll
            for (int p = 0; p < 4; ++p)
                v[(i + 1) & 1][p] =
                    *(const float4*)(sp + (size_t)(k0n + qq + (p << 4)) * C + cc4);
        }
        BAR_LGKM();                // loads stay in flight across this
        const int kc16 = (kt0 + i) << 3;
        ushort_t* run = dst + (((size_t)e * NT + (n0 >> 4) + w) * CK + kc16) * 128;
        #pragma unroll
        for (int p = 0; p < 2; ++p) {
            const int lidx = l + (p << 6);
            const int kc = lidx >> 4, nl = lidx & 15;
            const int col = (w << 4) + nl;
            short8 o;
            #pragma unroll
            for (int j = 0; j < 8; ++j)
                o[j] = (short)lb[((kc << 3) + j) * 68 + col];
            *(short8*)(run + (size_t)lidx * 8) = o;
        }
        // buffer reused 2 barriers later -> safe without a 2nd barrier.
    }
}

// offsets prefix-scan + 128-row tile list, wave-parallel (padded counts)
__global__ void scan_kernel(const int* __restrict__ counts, int* __restrict__ offsets,
                            int* __restrict__ tm, int* __restrict__ ntiles)
{
    const int lane = threadIdx.x;
    int c = (lane < NEXP) ? counts[lane * 16] : 0;
    int t = (c + 127) >> 7;
    int ic = c, it = t;
    #pragma unroll
    for (int off = 1; off < 16; off <<= 1) {
        const int pc = __shfl_up(ic, off, 64);
        const int pt = __shfl_up(it, off, 64);
        if (lane >= off) { ic += pc; it += pt; }
    }
    if (lane < NEXP) {
        offsets[lane] = ic - c;
        if (lane == NEXP - 1) { offsets[NEXP] = ic; ntiles[0] = it; }
        const int tb = it - t;
        for (int i = 0; i < t; ++i) tm[tb + i] = (lane << 16) | i;
    }
}

// gather x rows (fp32) into fragment-tiled bf16 A, slot order per 128-tile.
__global__ __launch_bounds__(256) void gather_xa(
    const float* __restrict__ x, const int* __restrict__ tok_list,
    const int* __restrict__ counts, const int* __restrict__ tm,
    const int* __restrict__ ntiles, ushort_t* __restrict__ xa)
{
    const int b = blockIdx.x;
    if (b >= ntiles[0]) return;
    const int info = tm[b];
    const int e = info >> 16, m0 = (info & 0xffff) << 7;
    const int Me = counts[e * 16];
    const int row = threadIdx.x >> 1;
    const int half = threadIdx.x & 1;
    const int kbase = blockIdx.y * 128 + half * 64;
    const int tok = tok_list[e * NTOK + min(m0 + row, Me - 1)];
    const float* src = x + (size_t)tok * DDIM + kbase;
    ushort_t* dstb = xa + (size_t)b * 65536 + (size_t)(row >> 4) * 8192 + (row & 15) * 8;
    #pragma unroll
    for (int q = 0; q < 16; ++q) {
        const int k = kbase + q * 4;
        const float4 v = *(const float4*)(src + q * 4);
        ushort4 o = make_ushort4(f2bf(v.x), f2bf(v.y), f2bf(v.z), f2bf(v.w));
        *(ushort4*)(dstb + (size_t)(k >> 3) * 128 + (k & 7)) = o;
    }
}

// ---- GEMM1: barrier-free K-loop, frags direct from global (tiled layouts) --
__global__ __launch_bounds__(256) void gemm1_mfma(
    const ushort_t* __restrict__ xa, const ushort_t* __restrict__ W1t,
    const float* __restrict__ b1, const int* __restrict__ tm,
    const int* __restrict__ ntiles, ushort_t* __restrict__ hb)
{
    const int t = blockIdx.y;
    if (t >= ntiles[0]) return;
    const int e = tm[t] >> 16;
    const int n0 = blockIdx.x << 7;
    const int tid = threadIdx.x, lane = tid & 63, w = tid >> 6;
    const int fm = lane & 15, fq = lane >> 4;
    const int wr = (w >> 1) << 6, wc = (w & 1) << 6;

    const ushort_t* baseA = xa + (size_t)t * 65536
                          + (size_t)((w >> 1) * 4) * 8192 + lane * 8;
    const ushort_t* baseB = W1t + ((size_t)e * 128 + (n0 >> 4) + (w & 1) * 4) * 8192
                          + lane * 8;

    floatx4 acc[4][4] = {};
    #pragma unroll 4
    for (int kc = 0; kc < 16; ++kc) {
        short8 af[4], bf[4];
        #pragma unroll
        for (int i = 0; i < 4; ++i)
            af[i] = *(const short8*)(baseA + i * 8192 + kc * 512);
        #pragma unroll
        for (int j = 0; j < 4; ++j)
            bf[j] = *(const short8*)(baseB + j * 8192 + kc * 512);
        #pragma unroll
        for (int i = 0; i < 4; ++i)
            #pragma unroll
            for (int j = 0; j < 4; ++j)
                acc[i][j] = __builtin_amdgcn_mfma_f32_16x16x32_bf16(
                    af[i], bf[j], acc[i][j], 0, 0, 0);
    }

    __shared__ ushort_t ls[128 * 128];
    #pragma unroll
    for (int j = 0; j < 4; ++j) {
        const float bias = b1[(size_t)e * HDIM + n0 + wc + j * 16 + fm];
        #pragma unroll
        for (int i = 0; i < 4; ++i)
            #pragma unroll
            for (int r = 0; r < 4; ++r) {
                const int row = wr + i * 16 + fq * 4 + r;
                ls[row * 128 + wc + j * 16 + fm] =
                    f2bf(fmaxf(acc[i][j][r] + bias, 0.f));
            }
    }
    __syncthreads();
    ushort_t* hbase = hb + (size_t)t * 262144 + (size_t)(n0 >> 3) * 128;
    #pragma unroll
    for (int p = 0; p < 8; ++p) {
        const int unit = tid + p * 256;
        const int row = unit >> 4, c16 = unit & 15;
        *(short8*)(hbase + (size_t)(row >> 4) * 32768 + (size_t)c16 * 128
                   + (row & 15) * 8) = *(const short8*)&ls[row * 128 + c16 * 8];
    }
}

// ---- GEMM2: same structure, K=2048 split-K=2, bf16 partials to ybuf -------
__global__ __launch_bounds__(256) void gemm2_mfma(
    const ushort_t* __restrict__ hb, const ushort_t* __restrict__ W2t,
    const float* __restrict__ b2, const float* __restrict__ w_list,
    const int* __restrict__ counts, const int* __restrict__ offsets,
    const int* __restrict__ tm, const int* __restrict__ ntiles,
    ushort_t* __restrict__ yb)
{
    const int t = blockIdx.y;
    if (t >= ntiles[0]) return;
    const int info = tm[t];
    const int e = info >> 16, m0 = (info & 0xffff) << 7;
    const int Me = counts[e * 16], aoff = offsets[e];
    const int n0 = blockIdx.x << 7;
    const int kz = blockIdx.z;
    const int tid = threadIdx.x, lane = tid & 63, w = tid >> 6;
    const int fm = lane & 15, fq = lane >> 4;
    const int wr = (w >> 1) << 6, wc = (w & 1) << 6;

    const ushort_t* baseA = hb + (size_t)t * 262144
                          + (size_t)((w >> 1) * 4) * 32768 + kz * 16384 + lane * 8;
    const ushort_t* baseB = W2t + ((size_t)e * 32 + (n0 >> 4) + (w & 1) * 4) * 32768
                          + kz * 16384 + lane * 8;

    floatx4 acc[4][4] = {};
    #pragma unroll 4
    for (int kc = 0; kc < 32; ++kc) {
        short8 af[4], bf[4];
        #pragma unroll
        for (int i = 0; i < 4; ++i)
            af[i] = *(const short8*)(baseA + i * 32768 + kc * 512);
        #pragma unroll
        for (int j = 0; j < 4; ++j)
            bf[j] = *(const short8*)(baseB + j * 32768 + kc * 512);
        #pragma unroll
        for (int i = 0; i < 4; ++i)
            #pragma unroll
            for (int j = 0; j < 4; ++j)
                acc[i][j] = __builtin_amdgcn_mfma_f32_16x16x32_bf16(
                    af[i], bf[j], acc[i][j], 0, 0, 0);
    }

    __shared__ ushort_t ls[128 * 128];
    #pragma unroll
    for (int j = 0; j < 4; ++j) {
        const float bias = (kz == 0) ? b2[(size_t)e * DDIM + n0 + wc + j * 16 + fm] : 0.f;
        #pragma unroll
        for (int i = 0; i < 4; ++i)
            #pragma unroll
            for (int r = 0; r < 4; ++r) {
                const int row = wr + i * 16 + fq * 4 + r;
                const float gw = w_list[e * NTOK + min(m0 + row, Me - 1)];
                ls[row * 128 + wc + j * 16 + fm] = f2bf(gw * (acc[i][j][r] + bias));
            }
    }
    __syncthreads();
    ushort_t* ybase = yb + (size_t)kz * (8192 * 512) + n0;
    #pragma unroll
    for (int p = 0; p < 8; ++p) {
        const int unit = tid + p * 256;
        const int row = unit >> 4, c16 = unit & 15;
        if (m0 + row < Me)
            *(short8*)(ybase + (size_t)(aoff + m0 + row) * 512 + c16 * 8)
                = *(const short8*)&ls[row * 128 + c16 * 8];
    }
}

// out = LayerNorm(x + y[0][r0] + y[1][r0] + y[0][r1] + y[1][r1]) * gamma + beta
__global__ __launch_bounds__(256) void ln_kernel(
    const float* __restrict__ x, const ushort_t* __restrict__ yb,
    const int* __restrict__ epos, const int* __restrict__ offsets,
    const float* __restrict__ gamma, const float* __restrict__ beta,
    float* __restrict__ out)
{
    const int t = blockIdx.x * 4 + (threadIdx.x >> 6);
    const int lane = threadIdx.x & 63;
    const int d0 = lane * 8;

    const int p0 = epos[2 * t + 0];
    const int p1 = epos[2 * t + 1];
    const size_t r0 = (size_t)(offsets[p0 >> 16] + (p0 & 0xFFFF));
    const size_t r1 = (size_t)(offsets[p1 >> 16] + (p1 & 0xFFFF));

    const short8 y0 = *(const short8*)(yb + r0 * 512 + d0);
    const short8 y1 = *(const short8*)(yb + (size_t)8192 * 512 + r0 * 512 + d0);
    const short8 y2 = *(const short8*)(yb + r1 * 512 + d0);
    const short8 y3 = *(const short8*)(yb + (size_t)8192 * 512 + r1 * 512 + d0);
    float xv[8];
    *(float4*)&xv[0] = *(const float4*)(x + (size_t)t * DDIM + d0);
    *(float4*)&xv[4] = *(const float4*)(x + (size_t)t * DDIM + d0 + 4);

    float v[8];
    float s = 0.f;
    #pragma unroll
    for (int i = 0; i < 8; ++i) {
        v[i] = xv[i] + bf2f((ushort_t)y0[i]) + bf2f((ushort_t)y1[i])
                     + bf2f((ushort_t)y2[i]) + bf2f((ushort_t)y3[i]);
        s += v[i];
    }
    #pragma unroll
    for (int o = 32; o > 0; o >>= 1) s += __shfl_xor(s, o, 64);
    const float mu = s * (1.f / DDIM);
    float q = 0.f;
    #pragma unroll
    for (int i = 0; i < 8; ++i) { const float d_ = v[i] - mu; q = fmaf(d_, d_, q); }
    #pragma unroll
    for (int o = 32; o > 0; o >>= 1) q += __shfl_xor(q, o, 64);
    const float rstd = rsqrtf(q * (1.f / DDIM) + 1e-5f);

    float g[8], bt[8], o8[8];
    *(float4*)&g[0] = *(const float4*)(gamma + d0);
    *(float4*)&g[4] = *(const float4*)(gamma + d0 + 4);
    *(float4*)&bt[0] = *(const float4*)(beta + d0);
    *(float4*)&bt[4] = *(const float4*)(beta + d0 + 4);
    #pragma unroll
    for (int i = 0; i < 8; ++i) o8[i] = (v[i] - mu) * rstd * g[i] + bt[i];
    *(float4*)(out + (size_t)t * DDIM + d0) = *(float4*)&o8[0];
    *(float4*)(out + (size_t)t * DDIM + d0 + 4) = *(float4*)&o8[4];
}

extern "C" void kernel_launch(void* const* d_in, const int* in_sizes, int n_in,
                              void* d_out, int out_size, void* d_ws, size_t ws_size,
                              hipStream_t stream) {
    const float* x     = (const float*)d_in[0];
    const float* Wg    = (const float*)d_in[1];
    const float* bg    = (const float*)d_in[2];
    const float* W1    = (const float*)d_in[3];
    const float* b1    = (const float*)d_in[4];
    const float* W2    = (const float*)d_in[5];
    const float* b2    = (const float*)d_in[6];
    const float* gamma = (const float*)d_in[7];
    const float* beta  = (const float*)d_in[8];
    float* out = (float*)d_out;

    char* ws = (char*)d_ws;
    int*      counts   = (int*)(ws + WS_COUNTS);
    int*      offsets  = (int*)(ws + WS_OFFSETS);
    int*      ntiles   = (int*)(ws + WS_NTILES);
    int*      tm       = (int*)(ws + WS_TM);
    int*      epos     = (int*)(ws + WS_EPOS);
    int*      tok_list = (int*)(ws + WS_TOK);
    float*    w_list   = (float*)(ws + WS_WL);
    ushort_t* xa       = (ushort_t*)(ws + WS_XA);
    ushort_t* W1t      = (ushort_t*)(ws + WS_W1T);
    ushort_t* W2t      = (ushort_t*)(ws + WS_W2T);
    ushort_t* hb       = (ushort_t*)(ws + WS_HB);
    ushort_t* yb       = (ushort_t*)(ws + WS_YB);   // aliases W1t (dead by then)

    hipMemsetAsync(counts, 0, 1024, stream);
    prep_kernel<<<1536, 256, 0, stream>>>(x, Wg, bg, W1, W2, counts,
                                          tok_list, w_list, epos, W1t, W2t);
    scan_kernel<<<1, 64, 0, stream>>>(counts, offsets, tm, ntiles);
    gather_xa<<<dim3(80, 4), 256, 0, stream>>>(x, tok_list, counts, tm, ntiles, xa);
    gemm1_mfma<<<dim3(HDIM / 128, 80), 256, 0, stream>>>(
        xa, W1t, b1, tm, ntiles, hb);
    gemm2_mfma<<<dim3(DDIM / 128, 80, 2), 256, 0, stream>>>(
        hb, W2t, b2, w_list, counts, offsets, tm, ntiles, yb);
    ln_kernel<<<NTOK / 4, 256, 0, stream>>>(x, yb, epos, offsets, gamma, beta, out);
}